// Round 1
// baseline (1945.570 us; speedup 1.0000x reference)
//
#include <hip/hip_runtime.h>
#include <math.h>

#define N_NODES 50000
#define IN_DIM 8
#define HID 32
#define D1 128   // HID * HEADS

// ---------------------------------------------------------------------------
// Kernel A: per-node linear 1.  One block (128 threads) per node.
//   Wh1[n][j] = sum_k x[n][k] * W1[k][j]
//   s1[n] = Wh1[n] . a1[0:128],  d1[n] = Wh1[n] . a1[128:256]
// ---------------------------------------------------------------------------
__global__ void k_node_lin1(const float* __restrict__ x,
                            const float* __restrict__ W1,
                            const float* __restrict__ a1,
                            float* __restrict__ Wh1,
                            float* __restrict__ s1,
                            float* __restrict__ d1) {
    const int node = blockIdx.x;
    const int j = threadIdx.x;                 // 0..127
    __shared__ float xs[IN_DIM];
    __shared__ float red_s[D1];
    __shared__ float red_d[D1];
    if (j < IN_DIM) xs[j] = x[node * IN_DIM + j];
    __syncthreads();
    float acc = 0.f;
#pragma unroll
    for (int k = 0; k < IN_DIM; ++k) acc += xs[k] * W1[k * D1 + j];
    Wh1[node * D1 + j] = acc;
    red_s[j] = acc * a1[j];
    red_d[j] = acc * a1[D1 + j];
    __syncthreads();
    for (int off = D1 / 2; off > 0; off >>= 1) {
        if (j < off) { red_s[j] += red_s[j + off]; red_d[j] += red_d[j + off]; }
        __syncthreads();
    }
    if (j == 0) { s1[node] = red_s[0]; d1[node] = red_d[0]; }
}

// ---------------------------------------------------------------------------
// Kernel B: per-edge attention logit -> exp, atomic segment sum over dst.
// (global alpha.max() subtraction skipped: cancels up to ~1e-10 relative)
// ---------------------------------------------------------------------------
__global__ void k_edge_alpha(const int* __restrict__ src,
                             const int* __restrict__ dst,
                             const float* __restrict__ s,
                             const float* __restrict__ d,
                             float* __restrict__ aexp,
                             float* __restrict__ asum,
                             int n_edges) {
    int e = blockIdx.x * blockDim.x + threadIdx.x;
    if (e >= n_edges) return;
    float a = s[src[e]] + d[dst[e]];
    a = a > 0.f ? a : 0.2f * a;               // leaky_relu(0.2)
    float ex = expf(a);
    aexp[e] = ex;
    atomicAdd(&asum[dst[e]], ex);
}

// ---------------------------------------------------------------------------
// Kernel C: weighted scatter  out[dst] += (aexp[e]/(asum[dst]+1e-9)) * Wh[src]
// D/4 threads per edge, float4 gathers, fp32 atomics.
// ---------------------------------------------------------------------------
template <int D>
__global__ void k_edge_scatter(const int* __restrict__ src,
                               const int* __restrict__ dst,
                               const float* __restrict__ aexp,
                               const float* __restrict__ asum,
                               const float* __restrict__ Wh,
                               float* __restrict__ out,
                               int n_edges) {
    const int groups = D / 4;
    int tid = blockIdx.x * blockDim.x + threadIdx.x;
    int e = tid / groups;
    int c = tid % groups;
    if (e >= n_edges) return;
    const int de = dst[e];
    const float w = aexp[e] / (asum[de] + 1e-9f);
    const float4 v = *(const float4*)&Wh[(long long)src[e] * D + c * 4];
    float* o = &out[(long long)de * D + c * 4];
    atomicAdd(o + 0, w * v.x);
    atomicAdd(o + 1, w * v.y);
    atomicAdd(o + 2, w * v.z);
    atomicAdd(o + 3, w * v.w);
}

// ---------------------------------------------------------------------------
// Kernel D: elu -> linear2 -> attention scalars.  One block (128 thr) / node.
// ---------------------------------------------------------------------------
__global__ void k_node_mid(const float* __restrict__ out1,
                           const float* __restrict__ W2,
                           const float* __restrict__ a2,
                           float* __restrict__ Wh2,
                           float* __restrict__ s2,
                           float* __restrict__ d2) {
    const int node = blockIdx.x;
    const int t = threadIdx.x;                 // 0..127
    __shared__ float h[D1];
    __shared__ float red_s[HID];
    __shared__ float red_d[HID];
    float v = out1[node * D1 + t];
    h[t] = v > 0.f ? v : (expf(v) - 1.f);      // elu
    __syncthreads();
    if (t < HID) {
        float acc = 0.f;
#pragma unroll 8
        for (int k = 0; k < D1; ++k) acc += h[k] * W2[k * HID + t];
        Wh2[node * HID + t] = acc;
        red_s[t] = acc * a2[t];
        red_d[t] = acc * a2[HID + t];
    }
    __syncthreads();
    if (t == 0) {
        float ss = 0.f, dd = 0.f;
        for (int k = 0; k < HID; ++k) { ss += red_s[k]; dd += red_d[k]; }
        s2[node] = ss;
        d2[node] = dd;
    }
}

// ---------------------------------------------------------------------------
// Kernel G: final head.  One thread per node: elu -> gelu(h@hw1+hb1) -> @hw2.
// ---------------------------------------------------------------------------
__global__ void k_head(const float* __restrict__ out2,
                       const float* __restrict__ hw1,
                       const float* __restrict__ hb1,
                       const float* __restrict__ hw2,
                       const float* __restrict__ hb2,
                       float* __restrict__ scores) {
    int node = blockIdx.x * blockDim.x + threadIdx.x;
    if (node >= N_NODES) return;
    float h[HID];
#pragma unroll
    for (int k = 0; k < HID; ++k) {
        float v = out2[node * HID + k];
        h[k] = v > 0.f ? v : (expf(v) - 1.f);  // elu
    }
    float score = hb2[0];
    for (int j = 0; j < HID; ++j) {
        float acc = hb1[j];
#pragma unroll
        for (int k = 0; k < HID; ++k) acc += h[k] * hw1[k * HID + j];
        // exact gelu: 0.5*x*(1+erf(x/sqrt(2)))
        float z = 0.5f * acc * (1.f + erff(acc * 0.7071067811865475f));
        score += z * hw2[j];
    }
    scores[node] = score;
}

// ---------------------------------------------------------------------------
extern "C" void kernel_launch(void* const* d_in, const int* in_sizes, int n_in,
                              void* d_out, int out_size, void* d_ws, size_t ws_size,
                              hipStream_t stream) {
    const float* x   = (const float*)d_in[0];
    const int*   ei  = (const int*)d_in[1];
    const float* W1  = (const float*)d_in[2];
    const float* a1  = (const float*)d_in[3];
    const float* W2  = (const float*)d_in[4];
    const float* a2  = (const float*)d_in[5];
    const float* hw1 = (const float*)d_in[6];
    const float* hb1 = (const float*)d_in[7];
    const float* hw2 = (const float*)d_in[8];
    const float* hb2 = (const float*)d_in[9];
    float* out = (float*)d_out;

    const int n_edges = in_sizes[1] / 2;
    const int* src = ei;
    const int* dst = ei + n_edges;

    // workspace carve-up (floats)
    float* p = (float*)d_ws;
    float* Wh1   = p; p += (size_t)N_NODES * D1;
    float* out1  = p; p += (size_t)N_NODES * D1;
    float* Wh2   = p; p += (size_t)N_NODES * HID;
    float* out2  = p; p += (size_t)N_NODES * HID;
    float* s1    = p; p += N_NODES;
    float* d1    = p; p += N_NODES;
    float* s2    = p; p += N_NODES;
    float* d2    = p; p += N_NODES;
    float* asum1 = p; p += N_NODES;
    float* asum2 = p; p += N_NODES;
    float* aexp1 = p; p += n_edges;
    float* aexp2 = p; p += n_edges;

    hipMemsetAsync(asum1, 0, N_NODES * sizeof(float), stream);
    hipMemsetAsync(asum2, 0, N_NODES * sizeof(float), stream);
    hipMemsetAsync(out1, 0, (size_t)N_NODES * D1 * sizeof(float), stream);
    hipMemsetAsync(out2, 0, (size_t)N_NODES * HID * sizeof(float), stream);

    // ----- layer 1 -----
    k_node_lin1<<<N_NODES, D1, 0, stream>>>(x, W1, a1, Wh1, s1, d1);
    k_edge_alpha<<<(n_edges + 255) / 256, 256, 0, stream>>>(src, dst, s1, d1,
                                                            aexp1, asum1, n_edges);
    {
        int total = n_edges * (D1 / 4);
        k_edge_scatter<D1><<<(total + 255) / 256, 256, 0, stream>>>(
            src, dst, aexp1, asum1, Wh1, out1, n_edges);
    }
    // ----- layer 2 -----
    k_node_mid<<<N_NODES, D1, 0, stream>>>(out1, W2, a2, Wh2, s2, d2);
    k_edge_alpha<<<(n_edges + 255) / 256, 256, 0, stream>>>(src, dst, s2, d2,
                                                            aexp2, asum2, n_edges);
    {
        int total = n_edges * (HID / 4);
        k_edge_scatter<HID><<<(total + 255) / 256, 256, 0, stream>>>(
            src, dst, aexp2, asum2, Wh2, out2, n_edges);
    }
    // ----- head -----
    k_head<<<(N_NODES + 255) / 256, 256, 0, stream>>>(out2, hw1, hb1, hw2, hb2, out);
}

// Round 2
// 498.862 us; speedup vs baseline: 3.9000x; 3.9000x over previous
//
#include <hip/hip_runtime.h>
#include <math.h>

#define N_NODES 50000
#define IN_DIM 8
#define HID 32
#define D1 128   // HID * HEADS
#define SCAN_T 1024

// ---------------------------------------------------------------------------
// Kernel A: per-node linear 1.  One block (128 threads) per node.
// ---------------------------------------------------------------------------
__global__ void k_node_lin1(const float* __restrict__ x,
                            const float* __restrict__ W1,
                            const float* __restrict__ a1,
                            float* __restrict__ Wh1,
                            float* __restrict__ s1,
                            float* __restrict__ d1) {
    const int node = blockIdx.x;
    const int j = threadIdx.x;                 // 0..127
    __shared__ float xs[IN_DIM];
    __shared__ float red_s[D1];
    __shared__ float red_d[D1];
    if (j < IN_DIM) xs[j] = x[node * IN_DIM + j];
    __syncthreads();
    float acc = 0.f;
#pragma unroll
    for (int k = 0; k < IN_DIM; ++k) acc += xs[k] * W1[k * D1 + j];
    Wh1[node * D1 + j] = acc;
    red_s[j] = acc * a1[j];
    red_d[j] = acc * a1[D1 + j];
    __syncthreads();
    for (int off = D1 / 2; off > 0; off >>= 1) {
        if (j < off) { red_s[j] += red_s[j + off]; red_d[j] += red_d[j + off]; }
        __syncthreads();
    }
    if (j == 0) { s1[node] = red_s[0]; d1[node] = red_d[0]; }
}

// ---------------------------------------------------------------------------
// CSR build: histogram -> exclusive scan -> fill (src ids sorted by dst)
// ---------------------------------------------------------------------------
__global__ void k_hist(const int* __restrict__ dst, int* __restrict__ cnt,
                       int n_edges) {
    int e = blockIdx.x * blockDim.x + threadIdx.x;
    if (e >= n_edges) return;
    atomicAdd(&cnt[dst[e]], 1);
}

__global__ void k_scan(const int* __restrict__ cnt, int* __restrict__ offs) {
    __shared__ int partial[SCAN_T];
    const int t = threadIdx.x;
    const int CHUNK = (N_NODES + SCAN_T - 1) / SCAN_T;   // 49
    const int base = t * CHUNK;
    int sum = 0;
    for (int i = 0; i < CHUNK; ++i) {
        int idx = base + i;
        if (idx < N_NODES) sum += cnt[idx];
    }
    partial[t] = sum;
    __syncthreads();
    for (int off = 1; off < SCAN_T; off <<= 1) {
        int v = (t >= off) ? partial[t - off] : 0;
        __syncthreads();
        partial[t] += v;
        __syncthreads();
    }
    int run = (t == 0) ? 0 : partial[t - 1];             // exclusive prefix
    for (int i = 0; i < CHUNK; ++i) {
        int idx = base + i;
        if (idx < N_NODES) { offs[idx] = run; run += cnt[idx]; }
    }
    if (t == SCAN_T - 1) offs[N_NODES] = run;            // total = n_edges
}

__global__ void k_fill(const int* __restrict__ src, const int* __restrict__ dst,
                       const int* __restrict__ offs, int* __restrict__ cursor,
                       int* __restrict__ esrc, int n_edges) {
    int e = blockIdx.x * blockDim.x + threadIdx.x;
    if (e >= n_edges) return;
    int d = dst[e];
    int pos = offs[d] + atomicAdd(&cursor[d], 1);
    esrc[pos] = src[e];
}

// ---------------------------------------------------------------------------
// Aggregation, D=128: one wave (64 lanes) per node, float2 per lane.
// Phase 1: lane-parallel softmax denominator.  Phase 2: sequential edge loop,
// weight recomputed by every lane (VALU is idle), coalesced 512B row gathers.
// ---------------------------------------------------------------------------
__global__ void k_aggr128(const int* __restrict__ esrc, const int* __restrict__ offs,
                          const float* __restrict__ s, const float* __restrict__ d,
                          const float* __restrict__ Wh, float* __restrict__ out) {
    const int wave = (blockIdx.x * blockDim.x + threadIdx.x) >> 6;
    const int lane = threadIdx.x & 63;
    if (wave >= N_NODES) return;
    const int start = offs[wave], end = offs[wave + 1];
    const float dn = d[wave];
    float sum = 0.f;
    for (int e = start + lane; e < end; e += 64) {
        float a = s[esrc[e]] + dn;
        a = a > 0.f ? a : 0.2f * a;
        sum += expf(a);
    }
#pragma unroll
    for (int off = 32; off > 0; off >>= 1) sum += __shfl_xor(sum, off);
    const float inv = 1.f / (sum + 1e-9f);
    float2 acc = {0.f, 0.f};
    for (int e = start; e < end; ++e) {
        int se = esrc[e];                                 // wave-uniform
        float a = s[se] + dn;
        a = a > 0.f ? a : 0.2f * a;
        float w = expf(a) * inv;
        float2 v = *(const float2*)&Wh[(size_t)se * D1 + lane * 2];
        acc.x += w * v.x;
        acc.y += w * v.y;
    }
    *(float2*)&out[(size_t)wave * D1 + lane * 2] = acc;
}

// ---------------------------------------------------------------------------
// Aggregation, D=32: one wave per node, 2 edges per iteration (lane = 32*j+c).
// ---------------------------------------------------------------------------
__global__ void k_aggr32(const int* __restrict__ esrc, const int* __restrict__ offs,
                         const float* __restrict__ s, const float* __restrict__ d,
                         const float* __restrict__ Wh, float* __restrict__ out) {
    const int wave = (blockIdx.x * blockDim.x + threadIdx.x) >> 6;
    const int lane = threadIdx.x & 63;
    if (wave >= N_NODES) return;
    const int start = offs[wave], end = offs[wave + 1];
    const float dn = d[wave];
    float sum = 0.f;
    for (int e = start + lane; e < end; e += 64) {
        float a = s[esrc[e]] + dn;
        a = a > 0.f ? a : 0.2f * a;
        sum += expf(a);
    }
#pragma unroll
    for (int off = 32; off > 0; off >>= 1) sum += __shfl_xor(sum, off);
    const float inv = 1.f / (sum + 1e-9f);
    const int j = lane >> 5;                              // 0/1: which edge
    const int c = lane & 31;                              // column
    float acc = 0.f;
    for (int e0 = start; e0 < end; e0 += 2) {
        int e = e0 + j;
        if (e < end) {
            int se = esrc[e];
            float a = s[se] + dn;
            a = a > 0.f ? a : 0.2f * a;
            float w = expf(a) * inv;
            acc += w * Wh[(size_t)se * HID + c];
        }
    }
    acc += __shfl_xor(acc, 32);
    if (lane < 32) out[(size_t)wave * HID + c] = acc;
}

// ---------------------------------------------------------------------------
// Kernel D: elu -> linear2 -> attention scalars.  One block (128 thr) / node.
// ---------------------------------------------------------------------------
__global__ void k_node_mid(const float* __restrict__ out1,
                           const float* __restrict__ W2,
                           const float* __restrict__ a2,
                           float* __restrict__ Wh2,
                           float* __restrict__ s2,
                           float* __restrict__ d2) {
    const int node = blockIdx.x;
    const int t = threadIdx.x;                 // 0..127
    __shared__ float h[D1];
    __shared__ float red_s[HID];
    __shared__ float red_d[HID];
    float v = out1[node * D1 + t];
    h[t] = v > 0.f ? v : (expf(v) - 1.f);      // elu
    __syncthreads();
    if (t < HID) {
        float acc = 0.f;
#pragma unroll 8
        for (int k = 0; k < D1; ++k) acc += h[k] * W2[k * HID + t];
        Wh2[node * HID + t] = acc;
        red_s[t] = acc * a2[t];
        red_d[t] = acc * a2[HID + t];
    }
    __syncthreads();
    if (t == 0) {
        float ss = 0.f, dd = 0.f;
        for (int k = 0; k < HID; ++k) { ss += red_s[k]; dd += red_d[k]; }
        s2[node] = ss;
        d2[node] = dd;
    }
}

// ---------------------------------------------------------------------------
// Final head.  One thread per node: elu -> gelu(h@hw1+hb1) -> @hw2 + hb2.
// ---------------------------------------------------------------------------
__global__ void k_head(const float* __restrict__ out2,
                       const float* __restrict__ hw1,
                       const float* __restrict__ hb1,
                       const float* __restrict__ hw2,
                       const float* __restrict__ hb2,
                       float* __restrict__ scores) {
    int node = blockIdx.x * blockDim.x + threadIdx.x;
    if (node >= N_NODES) return;
    float h[HID];
#pragma unroll
    for (int k = 0; k < HID; ++k) {
        float v = out2[node * HID + k];
        h[k] = v > 0.f ? v : (expf(v) - 1.f);  // elu
    }
    float score = hb2[0];
    for (int j = 0; j < HID; ++j) {
        float acc = hb1[j];
#pragma unroll
        for (int k = 0; k < HID; ++k) acc += h[k] * hw1[k * HID + j];
        float z = 0.5f * acc * (1.f + erff(acc * 0.7071067811865475f));
        score += z * hw2[j];
    }
    scores[node] = score;
}

// ---------------------------------------------------------------------------
extern "C" void kernel_launch(void* const* d_in, const int* in_sizes, int n_in,
                              void* d_out, int out_size, void* d_ws, size_t ws_size,
                              hipStream_t stream) {
    const float* x   = (const float*)d_in[0];
    const int*   ei  = (const int*)d_in[1];
    const float* W1  = (const float*)d_in[2];
    const float* a1  = (const float*)d_in[3];
    const float* W2  = (const float*)d_in[4];
    const float* a2  = (const float*)d_in[5];
    const float* hw1 = (const float*)d_in[6];
    const float* hb1 = (const float*)d_in[7];
    const float* hw2 = (const float*)d_in[8];
    const float* hb2 = (const float*)d_in[9];
    float* out = (float*)d_out;

    const int n_edges = in_sizes[1] / 2;
    const int* src = ei;
    const int* dst = ei + n_edges;

    // workspace carve-up
    float* p = (float*)d_ws;
    float* Wh1  = p; p += (size_t)N_NODES * D1;
    float* out1 = p; p += (size_t)N_NODES * D1;
    float* Wh2  = p; p += (size_t)N_NODES * HID;
    float* out2 = p; p += (size_t)N_NODES * HID;
    float* s1   = p; p += N_NODES;
    float* d1   = p; p += N_NODES;
    float* s2   = p; p += N_NODES;
    float* d2   = p; p += N_NODES;
    int* cnt    = (int*)p; p += N_NODES;        // histogram counts
    int* cursor = (int*)p; p += N_NODES;        // fill cursors
    int* offs   = (int*)p; p += N_NODES + 1;    // CSR offsets
    int* esrc   = (int*)p; p += n_edges;        // src ids sorted by dst

    // zero the two counter arrays (contiguous)
    hipMemsetAsync(cnt, 0, 2 * N_NODES * sizeof(int), stream);

    const int EB = (n_edges + 255) / 256;
    const int WAVE_BLOCKS = (N_NODES * 64 + 255) / 256;

    // CSR build (reusable for both layers)
    k_hist<<<EB, 256, 0, stream>>>(dst, cnt, n_edges);
    k_scan<<<1, SCAN_T, 0, stream>>>(cnt, offs);
    k_fill<<<EB, 256, 0, stream>>>(src, dst, offs, cursor, esrc, n_edges);

    // ----- layer 1 -----
    k_node_lin1<<<N_NODES, D1, 0, stream>>>(x, W1, a1, Wh1, s1, d1);
    k_aggr128<<<WAVE_BLOCKS, 256, 0, stream>>>(esrc, offs, s1, d1, Wh1, out1);

    // ----- layer 2 -----
    k_node_mid<<<N_NODES, D1, 0, stream>>>(out1, W2, a2, Wh2, s2, d2);
    k_aggr32<<<WAVE_BLOCKS, 256, 0, stream>>>(esrc, offs, s2, d2, Wh2, out2);

    // ----- head -----
    k_head<<<(N_NODES + 255) / 256, 256, 0, stream>>>(out2, hw1, hb1, hw2, hb2, out);
}

// Round 3
// 392.059 us; speedup vs baseline: 4.9624x; 1.2724x over previous
//
#include <hip/hip_runtime.h>
#include <math.h>

#define N_NODES 50000
#define IN_DIM 8
#define HID 32
#define D1 128   // HID * HEADS
#define SCAN_T 1024

// ---------------------------------------------------------------------------
// CSR build: histogram -> exclusive scan -> fill (src ids sorted by dst)
// ---------------------------------------------------------------------------
__global__ void k_hist(const int* __restrict__ dst, int* __restrict__ cnt,
                       int n_edges) {
    int e = blockIdx.x * blockDim.x + threadIdx.x;
    if (e >= n_edges) return;
    atomicAdd(&cnt[dst[e]], 1);
}

__global__ void k_scan(const int* __restrict__ cnt, int* __restrict__ offs) {
    __shared__ int partial[SCAN_T];
    const int t = threadIdx.x;
    const int CHUNK = (N_NODES + SCAN_T - 1) / SCAN_T;   // 49
    const int base = t * CHUNK;
    int sum = 0;
    for (int i = 0; i < CHUNK; ++i) {
        int idx = base + i;
        if (idx < N_NODES) sum += cnt[idx];
    }
    partial[t] = sum;
    __syncthreads();
    for (int off = 1; off < SCAN_T; off <<= 1) {
        int v = (t >= off) ? partial[t - off] : 0;
        __syncthreads();
        partial[t] += v;
        __syncthreads();
    }
    int run = (t == 0) ? 0 : partial[t - 1];             // exclusive prefix
    for (int i = 0; i < CHUNK; ++i) {
        int idx = base + i;
        if (idx < N_NODES) { offs[idx] = run; run += cnt[idx]; }
    }
    if (t == SCAN_T - 1) offs[N_NODES] = run;            // total = n_edges
}

__global__ void k_fill(const int* __restrict__ src, const int* __restrict__ dst,
                       const int* __restrict__ offs, int* __restrict__ cursor,
                       int* __restrict__ esrc, int n_edges) {
    int e = blockIdx.x * blockDim.x + threadIdx.x;
    if (e >= n_edges) return;
    int d = dst[e];
    int pos = offs[d] + atomicAdd(&cursor[d], 1);
    esrc[pos] = src[e];
}

// ---------------------------------------------------------------------------
// s1/d1 via folded attention vectors:  s1[n] = x[n]·(W1 a_src), etc.
// Each block redundantly computes the two 8-vectors (2048 MACs) in LDS.
// ---------------------------------------------------------------------------
__global__ void k_sd1(const float* __restrict__ x, const float* __restrict__ W1,
                      const float* __restrict__ a1,
                      float* __restrict__ s1, float* __restrict__ d1) {
    __shared__ float bs[IN_DIM], bd[IN_DIM];
    const int t = threadIdx.x;
    if (t < 16) {
        const int k = t & 7;
        const float* av = a1 + ((t < 8) ? 0 : D1);
        float acc = 0.f;
        for (int j = 0; j < D1; ++j) acc += W1[k * D1 + j] * av[j];
        if (t < 8) bs[k] = acc; else bd[k] = acc;
    }
    __syncthreads();
    const int node = blockIdx.x * blockDim.x + t;
    if (node >= N_NODES) return;
    const float4 x0 = *(const float4*)&x[node * 8];
    const float4 x1 = *(const float4*)&x[node * 8 + 4];
    s1[node] = x0.x*bs[0] + x0.y*bs[1] + x0.z*bs[2] + x0.w*bs[3]
             + x1.x*bs[4] + x1.y*bs[5] + x1.z*bs[6] + x1.w*bs[7];
    d1[node] = x0.x*bd[0] + x0.y*bd[1] + x0.z*bd[2] + x0.w*bd[3]
             + x1.x*bd[4] + x1.y*bd[5] + x1.z*bd[6] + x1.w*bd[7];
}

// ---------------------------------------------------------------------------
// Layer-1 aggregation in INPUT space (8-dim):  xa[n] = sum_e w_e * x[src_e].
// One wave per node.  Pass 1: softmax denominator (lane-parallel).
// Pass 2: 64-edge chunks; per-lane weight then shuffle-broadcast; 8 lanes per
// edge (lane = 8*g + c), cross-group reduce at the end.
// ---------------------------------------------------------------------------
__global__ void k_aggr_x(const int* __restrict__ esrc, const int* __restrict__ offs,
                         const float* __restrict__ s, const float* __restrict__ d,
                         const float* __restrict__ x, float* __restrict__ xa) {
    const int node = (blockIdx.x * blockDim.x + threadIdx.x) >> 6;
    const int lane = threadIdx.x & 63;
    if (node >= N_NODES) return;
    const int start = offs[node], end = offs[node + 1];
    const float dn = d[node];
    float sum = 0.f;
    for (int e = start + lane; e < end; e += 64) {
        float a = s[esrc[e]] + dn;
        a = a > 0.f ? a : 0.2f * a;
        sum += expf(a);
    }
#pragma unroll
    for (int off = 32; off > 0; off >>= 1) sum += __shfl_xor(sum, off);
    const float inv = 1.f / (sum + 1e-9f);
    const int g = lane >> 3;     // edge slot within 8-edge group
    const int c = lane & 7;      // x component
    float acc = 0.f;
    for (int chunk = start; chunk < end; chunk += 64) {
        const int cnt = min(64, end - chunk);
        float wv = 0.f; int sev = 0;
        if (lane < cnt) {
            sev = esrc[chunk + lane];
            float a = s[sev] + dn;
            a = a > 0.f ? a : 0.2f * a;
            wv = expf(a) * inv;
        }
        for (int i = 0; i < cnt; i += 8) {
            const int idx = i + g;
            const float w = __shfl(wv, idx);
            const int se = __shfl(sev, idx);
            if (idx < cnt) acc += w * x[se * IN_DIM + c];
        }
    }
    acc += __shfl_xor(acc, 8);
    acc += __shfl_xor(acc, 16);
    acc += __shfl_xor(acc, 32);
    if (lane < 8) xa[node * IN_DIM + lane] = acc;
}

// ---------------------------------------------------------------------------
// Fused node mid:  Wh1row = xa@W1, elu -> h (LDS), Wh2 = h@W2, s2/d2.
// One block (128 threads) per node.
// ---------------------------------------------------------------------------
__global__ void k_node_mid(const float* __restrict__ xa,
                           const float* __restrict__ W1,
                           const float* __restrict__ W2,
                           const float* __restrict__ a2,
                           float* __restrict__ Wh2,
                           float* __restrict__ s2, float* __restrict__ d2) {
    const int node = blockIdx.x;
    const int t = threadIdx.x;                 // 0..127
    __shared__ float xs[IN_DIM];
    __shared__ float h[D1];
    __shared__ float red_s[HID];
    __shared__ float red_d[HID];
    if (t < IN_DIM) xs[t] = xa[node * IN_DIM + t];
    __syncthreads();
    float acc = 0.f;
#pragma unroll
    for (int k = 0; k < IN_DIM; ++k) acc += xs[k] * W1[k * D1 + t];
    h[t] = acc > 0.f ? acc : (expf(acc) - 1.f);   // elu
    __syncthreads();
    if (t < HID) {
        float a = 0.f;
#pragma unroll 8
        for (int k = 0; k < D1; ++k) a += h[k] * W2[k * HID + t];
        Wh2[node * HID + t] = a;
        red_s[t] = a * a2[t];
        red_d[t] = a * a2[HID + t];
    }
    __syncthreads();
    if (t == 0) {
        float ss = 0.f, dd = 0.f;
        for (int k = 0; k < HID; ++k) { ss += red_s[k]; dd += red_d[k]; }
        s2[node] = ss;
        d2[node] = dd;
    }
}

// ---------------------------------------------------------------------------
// Layer-2 aggregation, D=32: one wave per node, 2 edges per iteration,
// shuffle-broadcast weights (no redundant expf).
// ---------------------------------------------------------------------------
__global__ void k_aggr32(const int* __restrict__ esrc, const int* __restrict__ offs,
                         const float* __restrict__ s, const float* __restrict__ d,
                         const float* __restrict__ Wh, float* __restrict__ out) {
    const int node = (blockIdx.x * blockDim.x + threadIdx.x) >> 6;
    const int lane = threadIdx.x & 63;
    if (node >= N_NODES) return;
    const int start = offs[node], end = offs[node + 1];
    const float dn = d[node];
    float sum = 0.f;
    for (int e = start + lane; e < end; e += 64) {
        float a = s[esrc[e]] + dn;
        a = a > 0.f ? a : 0.2f * a;
        sum += expf(a);
    }
#pragma unroll
    for (int off = 32; off > 0; off >>= 1) sum += __shfl_xor(sum, off);
    const float inv = 1.f / (sum + 1e-9f);
    const int j2 = lane >> 5;    // which of 2 edges
    const int c = lane & 31;     // column
    float acc = 0.f;
    for (int chunk = start; chunk < end; chunk += 64) {
        const int cnt = min(64, end - chunk);
        float wv = 0.f; int sev = 0;
        if (lane < cnt) {
            sev = esrc[chunk + lane];
            float a = s[sev] + dn;
            a = a > 0.f ? a : 0.2f * a;
            wv = expf(a) * inv;
        }
        for (int i = 0; i < cnt; i += 2) {
            const int idx = i + j2;
            const float w = __shfl(wv, idx);
            const int se = __shfl(sev, idx);
            if (idx < cnt) acc += w * Wh[se * HID + c];
        }
    }
    acc += __shfl_xor(acc, 32);
    if (lane < 32) out[node * HID + lane] = acc;
}

// ---------------------------------------------------------------------------
// Final head.  One thread per node: elu -> gelu(h@hw1+hb1) -> @hw2 + hb2.
// ---------------------------------------------------------------------------
__global__ void k_head(const float* __restrict__ out2,
                       const float* __restrict__ hw1,
                       const float* __restrict__ hb1,
                       const float* __restrict__ hw2,
                       const float* __restrict__ hb2,
                       float* __restrict__ scores) {
    int node = blockIdx.x * blockDim.x + threadIdx.x;
    if (node >= N_NODES) return;
    float h[HID];
#pragma unroll
    for (int k = 0; k < HID; ++k) {
        float v = out2[node * HID + k];
        h[k] = v > 0.f ? v : (expf(v) - 1.f);  // elu
    }
    float score = hb2[0];
    for (int j = 0; j < HID; ++j) {
        float acc = hb1[j];
#pragma unroll
        for (int k = 0; k < HID; ++k) acc += h[k] * hw1[k * HID + j];
        float z = 0.5f * acc * (1.f + erff(acc * 0.7071067811865475f));
        score += z * hw2[j];
    }
    scores[node] = score;
}

// ---------------------------------------------------------------------------
extern "C" void kernel_launch(void* const* d_in, const int* in_sizes, int n_in,
                              void* d_out, int out_size, void* d_ws, size_t ws_size,
                              hipStream_t stream) {
    const float* x   = (const float*)d_in[0];
    const int*   ei  = (const int*)d_in[1];
    const float* W1  = (const float*)d_in[2];
    const float* a1  = (const float*)d_in[3];
    const float* W2  = (const float*)d_in[4];
    const float* a2  = (const float*)d_in[5];
    const float* hw1 = (const float*)d_in[6];
    const float* hb1 = (const float*)d_in[7];
    const float* hw2 = (const float*)d_in[8];
    const float* hb2 = (const float*)d_in[9];
    float* out = (float*)d_out;

    const int n_edges = in_sizes[1] / 2;
    const int* src = ei;
    const int* dst = ei + n_edges;

    // workspace carve-up
    float* p = (float*)d_ws;
    float* xa   = p; p += (size_t)N_NODES * IN_DIM;
    float* Wh2  = p; p += (size_t)N_NODES * HID;
    float* out2 = p; p += (size_t)N_NODES * HID;
    float* s1   = p; p += N_NODES;
    float* d1   = p; p += N_NODES;
    float* s2   = p; p += N_NODES;
    float* d2   = p; p += N_NODES;
    int* cnt    = (int*)p; p += N_NODES;        // histogram counts
    int* cursor = (int*)p; p += N_NODES;        // fill cursors
    int* offs   = (int*)p; p += N_NODES + 1;    // CSR offsets
    int* esrc   = (int*)p; p += n_edges;        // src ids sorted by dst

    hipMemsetAsync(cnt, 0, 2 * N_NODES * sizeof(int), stream);

    const int EB = (n_edges + 255) / 256;
    const int WAVE_BLOCKS = (N_NODES * 64 + 255) / 256;

    // CSR build (shared by both layers)
    k_hist<<<EB, 256, 0, stream>>>(dst, cnt, n_edges);
    k_scan<<<1, SCAN_T, 0, stream>>>(cnt, offs);
    k_fill<<<EB, 256, 0, stream>>>(src, dst, offs, cursor, esrc, n_edges);

    // ----- layer 1 (aggregated in 8-dim input space; Wh1 never built) -----
    k_sd1<<<(N_NODES + 255) / 256, 256, 0, stream>>>(x, W1, a1, s1, d1);
    k_aggr_x<<<WAVE_BLOCKS, 256, 0, stream>>>(esrc, offs, s1, d1, x, xa);

    // ----- layer 2 -----
    k_node_mid<<<N_NODES, D1, 0, stream>>>(xa, W1, W2, a2, Wh2, s2, d2);
    k_aggr32<<<WAVE_BLOCKS, 256, 0, stream>>>(esrc, offs, s2, d2, Wh2, out2);

    // ----- head -----
    k_head<<<(N_NODES + 255) / 256, 256, 0, stream>>>(out2, hw1, hb1, hw2, hb2, out);
}

// Round 4
// 284.284 us; speedup vs baseline: 6.8438x; 1.3791x over previous
//
#include <hip/hip_runtime.h>
#include <math.h>

#define N_NODES 50000
#define IN_DIM 8
#define HID 32
#define D1 128   // HID * HEADS

// hierarchical scan config: 256 thr × 4 elems = 1024 per block
#define SB 1024
#define NB ((N_NODES + SB - 1) / SB)   // 49

// ---------------------------------------------------------------------------
// CSR build: histogram -> 3-stage scan -> fill (src ids sorted by dst)
// ---------------------------------------------------------------------------
__global__ void k_hist(const int* __restrict__ dst, int* __restrict__ cnt,
                       int n_edges) {
    int e = blockIdx.x * blockDim.x + threadIdx.x;
    if (e >= n_edges) return;
    atomicAdd(&cnt[dst[e]], 1);
}

// stage A: per-block sums (49 blocks)
__global__ void k_scan_a(const int* __restrict__ cnt, int* __restrict__ bsum) {
    const int t = threadIdx.x;
    const int base = blockIdx.x * SB + t * 4;
    int4 v = {0, 0, 0, 0};
    if (base + 3 < N_NODES) v = *(const int4*)&cnt[base];
    int s = v.x + v.y + v.z + v.w;
#pragma unroll
    for (int off = 32; off > 0; off >>= 1) s += __shfl_xor(s, off);
    __shared__ int w[4];
    if ((t & 63) == 0) w[t >> 6] = s;
    __syncthreads();
    if (t == 0) bsum[blockIdx.x] = w[0] + w[1] + w[2] + w[3];
}

// stage B: one wave scans the 49 block sums; also writes offs[N_NODES]=total
__global__ void k_scan_b(const int* __restrict__ bsum, int* __restrict__ boff,
                         int* __restrict__ offs) {
    const int t = threadIdx.x;   // 64 threads
    int v = (t < NB) ? bsum[t] : 0;
    int incl = v;
#pragma unroll
    for (int off = 1; off < 64; off <<= 1) {
        int u = __shfl_up(incl, off);
        if (t >= off) incl += u;
    }
    if (t < NB) boff[t] = incl - v;       // exclusive
    if (t == 63) offs[N_NODES] = incl;    // grand total = n_edges
}

// stage C: per-block exclusive scan + global offset -> offs[]
__global__ void k_scan_c(const int* __restrict__ cnt, const int* __restrict__ boff,
                         int* __restrict__ offs) {
    const int t = threadIdx.x;
    const int lane = t & 63, wid = t >> 6;
    const int base = blockIdx.x * SB + t * 4;
    int4 v = {0, 0, 0, 0};
    if (base + 3 < N_NODES) v = *(const int4*)&cnt[base];
    const int tsum = v.x + v.y + v.z + v.w;
    int incl = tsum;
#pragma unroll
    for (int off = 1; off < 64; off <<= 1) {
        int u = __shfl_up(incl, off);
        if (lane >= off) incl += u;
    }
    __shared__ int wtot[4];
    if (lane == 63) wtot[wid] = incl;
    __syncthreads();
    int woff = 0;
    for (int w = 0; w < wid; ++w) woff += wtot[w];
    const int excl = boff[blockIdx.x] + woff + incl - tsum;
    if (base + 3 < N_NODES) {
        int4 o;
        o.x = excl;
        o.y = excl + v.x;
        o.z = excl + v.x + v.y;
        o.w = excl + v.x + v.y + v.z;
        *(int4*)&offs[base] = o;
    }
}

__global__ void k_fill(const int* __restrict__ src, const int* __restrict__ dst,
                       const int* __restrict__ offs, int* __restrict__ cursor,
                       int* __restrict__ esrc, int n_edges) {
    int e = blockIdx.x * blockDim.x + threadIdx.x;
    if (e >= n_edges) return;
    int d = dst[e];
    int pos = offs[d] + atomicAdd(&cursor[d], 1);
    esrc[pos] = src[e];
}

// ---------------------------------------------------------------------------
// s1/d1 via folded attention vectors:  s1[n] = x[n]·(W1 a_src), etc.
// ---------------------------------------------------------------------------
__global__ void k_sd1(const float* __restrict__ x, const float* __restrict__ W1,
                      const float* __restrict__ a1,
                      float* __restrict__ s1, float* __restrict__ d1) {
    __shared__ float bs[IN_DIM], bd[IN_DIM];
    const int t = threadIdx.x;
    if (t < 16) {
        const int k = t & 7;
        const float* av = a1 + ((t < 8) ? 0 : D1);
        float acc = 0.f;
        for (int j = 0; j < D1; ++j) acc += W1[k * D1 + j] * av[j];
        if (t < 8) bs[k] = acc; else bd[k] = acc;
    }
    __syncthreads();
    const int node = blockIdx.x * blockDim.x + t;
    if (node >= N_NODES) return;
    const float4 x0 = *(const float4*)&x[node * 8];
    const float4 x1 = *(const float4*)&x[node * 8 + 4];
    s1[node] = x0.x*bs[0] + x0.y*bs[1] + x0.z*bs[2] + x0.w*bs[3]
             + x1.x*bs[4] + x1.y*bs[5] + x1.z*bs[6] + x1.w*bs[7];
    d1[node] = x0.x*bd[0] + x0.y*bd[1] + x0.z*bd[2] + x0.w*bd[3]
             + x1.x*bd[4] + x1.y*bd[5] + x1.z*bd[6] + x1.w*bd[7];
}

// ---------------------------------------------------------------------------
// Layer-1 aggregation in INPUT space (8-dim):  xa[n] = sum_e w_e * x[src_e].
// ---------------------------------------------------------------------------
__global__ void k_aggr_x(const int* __restrict__ esrc, const int* __restrict__ offs,
                         const float* __restrict__ s, const float* __restrict__ d,
                         const float* __restrict__ x, float* __restrict__ xa) {
    const int node = (blockIdx.x * blockDim.x + threadIdx.x) >> 6;
    const int lane = threadIdx.x & 63;
    if (node >= N_NODES) return;
    const int start = offs[node], end = offs[node + 1];
    const float dn = d[node];
    float sum = 0.f;
    for (int e = start + lane; e < end; e += 64) {
        float a = s[esrc[e]] + dn;
        a = a > 0.f ? a : 0.2f * a;
        sum += expf(a);
    }
#pragma unroll
    for (int off = 32; off > 0; off >>= 1) sum += __shfl_xor(sum, off);
    const float inv = 1.f / (sum + 1e-9f);
    const int g = lane >> 3;     // edge slot within 8-edge group
    const int c = lane & 7;      // x component
    float acc = 0.f;
    for (int chunk = start; chunk < end; chunk += 64) {
        const int cnt = min(64, end - chunk);
        float wv = 0.f; int sev = 0;
        if (lane < cnt) {
            sev = esrc[chunk + lane];
            float a = s[sev] + dn;
            a = a > 0.f ? a : 0.2f * a;
            wv = expf(a) * inv;
        }
        for (int i = 0; i < cnt; i += 8) {
            const int idx = i + g;
            const float w = __shfl(wv, idx);
            const int se = __shfl(sev, idx);
            if (idx < cnt) acc += w * x[se * IN_DIM + c];
        }
    }
    acc += __shfl_xor(acc, 8);
    acc += __shfl_xor(acc, 16);
    acc += __shfl_xor(acc, 32);
    if (lane < 8) xa[node * IN_DIM + lane] = acc;
}

// ---------------------------------------------------------------------------
// Fused node mid: Wh1row = xa@W1, elu -> h (LDS), Wh2 = h@W2 (K split over 4
// segments so all 128 threads work), s2/d2 via shuffle reduce.
// ---------------------------------------------------------------------------
__global__ void k_node_mid(const float* __restrict__ xa,
                           const float* __restrict__ W1,
                           const float* __restrict__ W2,
                           const float* __restrict__ a2,
                           float* __restrict__ Wh2,
                           float* __restrict__ s2, float* __restrict__ d2) {
    const int node = blockIdx.x;
    const int t = threadIdx.x;                 // 0..127
    __shared__ float xs[IN_DIM];
    __shared__ float h[D1];
    __shared__ float red[4][HID];
    if (t < IN_DIM) xs[t] = xa[node * IN_DIM + t];
    __syncthreads();
    float acc = 0.f;
#pragma unroll
    for (int k = 0; k < IN_DIM; ++k) acc += xs[k] * W1[k * D1 + t];
    h[t] = acc > 0.f ? acc : (expf(acc) - 1.f);   // elu
    __syncthreads();
    {   // h @ W2 : col = t&31, K-segment = t>>5 (32 k's each)
        const int col = t & 31, seg = t >> 5;
        float a = 0.f;
#pragma unroll
        for (int k = seg * 32; k < seg * 32 + 32; ++k) a += h[k] * W2[k * HID + col];
        red[seg][col] = a;
    }
    __syncthreads();
    if (t < HID) {
        float a = red[0][t] + red[1][t] + red[2][t] + red[3][t];
        Wh2[node * HID + t] = a;
        float ss = a * a2[t];
        float dd = a * a2[HID + t];
#pragma unroll
        for (int off = 16; off > 0; off >>= 1) {
            ss += __shfl_xor(ss, off);
            dd += __shfl_xor(dd, off);
        }
        if (t == 0) { s2[node] = ss; d2[node] = dd; }
    }
}

// ---------------------------------------------------------------------------
// Layer-2 aggregation, D=32: one wave per node, 2 edges/iter, shuffle weights.
// ---------------------------------------------------------------------------
__global__ void k_aggr32(const int* __restrict__ esrc, const int* __restrict__ offs,
                         const float* __restrict__ s, const float* __restrict__ d,
                         const float* __restrict__ Wh, float* __restrict__ out) {
    const int node = (blockIdx.x * blockDim.x + threadIdx.x) >> 6;
    const int lane = threadIdx.x & 63;
    if (node >= N_NODES) return;
    const int start = offs[node], end = offs[node + 1];
    const float dn = d[node];
    float sum = 0.f;
    for (int e = start + lane; e < end; e += 64) {
        float a = s[esrc[e]] + dn;
        a = a > 0.f ? a : 0.2f * a;
        sum += expf(a);
    }
#pragma unroll
    for (int off = 32; off > 0; off >>= 1) sum += __shfl_xor(sum, off);
    const float inv = 1.f / (sum + 1e-9f);
    const int j2 = lane >> 5;    // which of 2 edges
    const int c = lane & 31;     // column
    float acc = 0.f;
    for (int chunk = start; chunk < end; chunk += 64) {
        const int cnt = min(64, end - chunk);
        float wv = 0.f; int sev = 0;
        if (lane < cnt) {
            sev = esrc[chunk + lane];
            float a = s[sev] + dn;
            a = a > 0.f ? a : 0.2f * a;
            wv = expf(a) * inv;
        }
        for (int i = 0; i < cnt; i += 2) {
            const int idx = i + j2;
            const float w = __shfl(wv, idx);
            const int se = __shfl(sev, idx);
            if (idx < cnt) acc += w * Wh[se * HID + c];
        }
    }
    acc += __shfl_xor(acc, 32);
    if (lane < 32) out[node * HID + lane] = acc;
}

// ---------------------------------------------------------------------------
// Final head.  One thread per node: elu -> gelu(h@hw1+hb1) -> @hw2 + hb2.
// ---------------------------------------------------------------------------
__global__ void k_head(const float* __restrict__ out2,
                       const float* __restrict__ hw1,
                       const float* __restrict__ hb1,
                       const float* __restrict__ hw2,
                       const float* __restrict__ hb2,
                       float* __restrict__ scores) {
    int node = blockIdx.x * blockDim.x + threadIdx.x;
    if (node >= N_NODES) return;
    float h[HID];
#pragma unroll
    for (int k = 0; k < HID; ++k) {
        float v = out2[node * HID + k];
        h[k] = v > 0.f ? v : (expf(v) - 1.f);  // elu
    }
    float score = hb2[0];
    for (int j = 0; j < HID; ++j) {
        float acc = hb1[j];
#pragma unroll
        for (int k = 0; k < HID; ++k) acc += h[k] * hw1[k * HID + j];
        float z = 0.5f * acc * (1.f + erff(acc * 0.7071067811865475f));
        score += z * hw2[j];
    }
    scores[node] = score;
}

// ---------------------------------------------------------------------------
extern "C" void kernel_launch(void* const* d_in, const int* in_sizes, int n_in,
                              void* d_out, int out_size, void* d_ws, size_t ws_size,
                              hipStream_t stream) {
    const float* x   = (const float*)d_in[0];
    const int*   ei  = (const int*)d_in[1];
    const float* W1  = (const float*)d_in[2];
    const float* a1  = (const float*)d_in[3];
    const float* W2  = (const float*)d_in[4];
    const float* a2  = (const float*)d_in[5];
    const float* hw1 = (const float*)d_in[6];
    const float* hb1 = (const float*)d_in[7];
    const float* hw2 = (const float*)d_in[8];
    const float* hb2 = (const float*)d_in[9];
    float* out = (float*)d_out;

    const int n_edges = in_sizes[1] / 2;
    const int* src = ei;
    const int* dst = ei + n_edges;

    // workspace carve-up
    float* p = (float*)d_ws;
    float* xa   = p; p += (size_t)N_NODES * IN_DIM;
    float* Wh2  = p; p += (size_t)N_NODES * HID;
    float* out2 = p; p += (size_t)N_NODES * HID;
    float* s1   = p; p += N_NODES;
    float* d1   = p; p += N_NODES;
    float* s2   = p; p += N_NODES;
    float* d2   = p; p += N_NODES;
    int* cnt    = (int*)p; p += N_NODES;        // histogram counts
    int* cursor = (int*)p; p += N_NODES;        // fill cursors
    int* offs   = (int*)p; p += N_NODES + 1;    // CSR offsets
    int* esrc   = (int*)p; p += n_edges;        // src ids sorted by dst
    int* bsum   = (int*)p; p += NB;             // scan block sums
    int* boff   = (int*)p; p += NB;             // scan block offsets

    hipMemsetAsync(cnt, 0, 2 * N_NODES * sizeof(int), stream);

    const int EB = (n_edges + 255) / 256;
    const int WAVE_BLOCKS = (N_NODES * 64 + 255) / 256;

    // CSR build (shared by both layers)
    k_hist<<<EB, 256, 0, stream>>>(dst, cnt, n_edges);
    k_scan_a<<<NB, 256, 0, stream>>>(cnt, bsum);
    k_scan_b<<<1, 64, 0, stream>>>(bsum, boff, offs);
    k_scan_c<<<NB, 256, 0, stream>>>(cnt, boff, offs);
    k_fill<<<EB, 256, 0, stream>>>(src, dst, offs, cursor, esrc, n_edges);

    // ----- layer 1 (aggregated in 8-dim input space; Wh1 never built) -----
    k_sd1<<<(N_NODES + 255) / 256, 256, 0, stream>>>(x, W1, a1, s1, d1);
    k_aggr_x<<<WAVE_BLOCKS, 256, 0, stream>>>(esrc, offs, s1, d1, x, xa);

    // ----- layer 2 -----
    k_node_mid<<<N_NODES, D1, 0, stream>>>(xa, W1, W2, a2, Wh2, s2, d2);
    k_aggr32<<<WAVE_BLOCKS, 256, 0, stream>>>(esrc, offs, s2, d2, Wh2, out2);

    // ----- head -----
    k_head<<<(N_NODES + 255) / 256, 256, 0, stream>>>(out2, hw1, hb1, hw2, hb2, out);
}